// Round 2
// baseline (94355.225 us; speedup 1.0000x reference)
//
// SCN-LSTM persistent-kernel implementation for MI355X (gfx950).  Round 2.
//
// Changes vs round 1 (which was 100% barrier-bound: 29.6us/barrier from a
// single fetch_add cacheline ping-ponging across 8 XCDs):
//  - Contention-free grid barrier: per-block padded arrival flags (plain
//    release stores to distinct 64B lines), block-0 wave-0 scans all 256
//    flags (4 pipelined loads/lane), releases a single `gen` word that
//    everyone polls read-only.  No atomic RMW anywhere.
//  - All tick-invariant operands hoisted OUT of the 1024-tick loop into
//    registers: phase-A weight fragments (16 x s16x8 = 64 VGPR), phase-B
//    weight fragments (32 x s16x8 = 128 VGPR), scale factors, biases,
//    pointers.  1 block/CU = 1 wave/SIMD -> 512 VGPR budget/wave
//    (__launch_bounds__(256,1)).  Per-tick global traffic is now only the
//    activations (h-state / x / P), all L2/L3-resident.
#include <hip/hip_runtime.h>

typedef unsigned short u16;
typedef __attribute__((ext_vector_type(8))) short s16x8;
typedef __attribute__((ext_vector_type(4))) float f32x4;
typedef __attribute__((ext_vector_type(4))) float float4v;

#define T_ 1024
#define OUT_HST 33554432   // 64*1024*512
#define OUT_CST 33619968   // + 64*2*512

// workspace byte offsets
#define WT_BYTES   (1u << 21)                // 2MB per transposed weight tensor (4x512x512 bf16)
#define OFF_SC     (8u * WT_BYTES)           // 16,777,216 : tb0, ub0, ub1, tb1 (4x4x64x512 f32)
#define OFF_P      (OFF_SC + 2097152u)       // 18,874,368 : P0..P3 (4 x 4x64x512 bf16)
#define OFF_HST    (OFF_P + 1048576u)        // 19,922,944 : h state, 2 layers, bf16
#define OFF_CSTATE (OFF_HST + 131072u)       // 20,054,016 : c state, 2 layers, f32
#define OFF_BAR    (OFF_CSTATE + 262144u)    // 20,316,160 : gen word + 256 padded flags

__device__ __forceinline__ u16 f2bf(float f) {
  union { float f; unsigned u; } v; v.f = f;
  return (u16)((v.u + 0x7FFFu + ((v.u >> 16) & 1u)) >> 16);
}

__device__ __forceinline__ s16x8 cvt8(const float* p) {
  float4v a = *(const float4v*)p;
  float4v b = *(const float4v*)(p + 4);
  s16x8 r;
  r[0] = (short)f2bf(a[0]); r[1] = (short)f2bf(a[1]);
  r[2] = (short)f2bf(a[2]); r[3] = (short)f2bf(a[3]);
  r[4] = (short)f2bf(b[0]); r[5] = (short)f2bf(b[1]);
  r[6] = (short)f2bf(b[2]); r[7] = (short)f2bf(b[3]);
  return r;
}

__device__ __forceinline__ f32x4 mfma_bf16(s16x8 a, s16x8 b, f32x4 c) {
  return __builtin_amdgcn_mfma_f32_16x16x32_bf16(a, b, c, 0, 0, 0);
}

// ---------------- prep kernels ----------------

struct SrcPtrs { const float* p[8]; };

// Transpose 8 weight tensors (4,512,512) f32 [g][k][n] -> (4,512,512) bf16 [g][n][k]
__global__ void prep_transpose(SrcPtrs s, unsigned char* ws) {
  __shared__ float tb[64][65];
  int bid = blockIdx.x, tid = threadIdx.x;
  int ten = bid >> 8, g = (bid >> 6) & 3, tile = bid & 63;
  int tk = (tile >> 3) << 6, tn = (tile & 7) << 6;
  const float* src = s.p[ten] + ((size_t)g << 18);
  u16* dst = (u16*)(ws + (size_t)ten * WT_BYTES) + ((size_t)g << 18);
  int c = tid & 63, i0 = tid >> 6;
  for (int i = i0; i < 64; i += 4)
    tb[i][c] = src[(size_t)(tk + i) * 512 + tn + c];
  __syncthreads();
  for (int i = i0; i < 64; i += 4)
    dst[(size_t)(tn + i) * 512 + tk + c] = f2bf(tb[c][i]);
}

// SC[m][g][b][f] = sum_k tag[b][k] * W_m[g][k][f], K=300.  m: tb0, ub0, ub1, tb1
__global__ void prep_scales(const float* tag, const float* w0, const float* w1,
                            const float* w2, const float* w3, unsigned char* ws) {
  int t = blockIdx.x * 256 + threadIdx.x;
  int f = t & 511, b = (t >> 9) & 63, g = (t >> 15) & 3, m = t >> 17;
  const float* W = (m == 0) ? w0 : (m == 1) ? w1 : (m == 2) ? w2 : w3;
  const float* tg = tag + b * 300;
  const float* wp = W + (size_t)(g * 300) * 512 + f;
  float acc = 0.f;
  for (int k = 0; k < 300; ++k) acc += tg[k] * wp[(size_t)k * 512];
  ((float*)(ws + OFF_SC))[((size_t)(m * 4 + g) * 64 + b) * 512 + f] = acc;
}

// init h/c state + barrier flags
__global__ void prep_state(const float* hh, const float* hc, unsigned char* ws) {
  int t = blockIdx.x * 256 + threadIdx.x;  // 0..65535
  u16* H = (u16*)(ws + OFF_HST);
  float* C = (float*)(ws + OFF_CSTATE);
  unsigned* bar = (unsigned*)(ws + OFF_BAR);
  if (t < 8192) bar[t] = 0u;   // gen word + all padded flags
  int L = t >> 15, r = t & 32767;
  int b = r >> 9, h = r & 511;
  float hv = hh[(size_t)b * 1024 + L * 512 + h];
  float cv = hc[(size_t)b * 1024 + L * 512 + h];
  H[t] = f2bf(hv);
  C[t] = cv;
}

// ---------------- grid barrier (contention-free) ----------------
// gen = bar[0..15] (one line); flag[i] = bar[16 + i*16] (own 64B line each).
__device__ __forceinline__ void gridbar(unsigned* gen, unsigned* flags,
                                        unsigned target, int bid, int tid) {
  __syncthreads();
  __threadfence();
  if (bid == 0) {
    if (tid < 64) {
      if (tid == 0)
        __hip_atomic_store(flags, target, __ATOMIC_RELAXED, __HIP_MEMORY_SCOPE_AGENT);
      const unsigned* f0 = flags + tid * 64;  // lane watches flags tid*4 .. tid*4+3
      long spin = 0;
      for (;;) {
        unsigned a = __hip_atomic_load(f0 +  0, __ATOMIC_RELAXED, __HIP_MEMORY_SCOPE_AGENT);
        unsigned b = __hip_atomic_load(f0 + 16, __ATOMIC_RELAXED, __HIP_MEMORY_SCOPE_AGENT);
        unsigned c = __hip_atomic_load(f0 + 32, __ATOMIC_RELAXED, __HIP_MEMORY_SCOPE_AGENT);
        unsigned d = __hip_atomic_load(f0 + 48, __ATOMIC_RELAXED, __HIP_MEMORY_SCOPE_AGENT);
        bool ok = (a >= target) & (b >= target) & (c >= target) & (d >= target);
        if (__all((int)ok)) break;
        __builtin_amdgcn_s_sleep(1);
        if (++spin > (1L << 22)) break;  // safety: never hang the harness
      }
      if (tid == 0) {
        __threadfence();
        __hip_atomic_store(gen, target, __ATOMIC_RELEASE, __HIP_MEMORY_SCOPE_AGENT);
      }
    }
  } else if (tid == 0) {
    __hip_atomic_store(flags + bid * 16, target, __ATOMIC_RELAXED, __HIP_MEMORY_SCOPE_AGENT);
    long spin = 0;
    while (__hip_atomic_load(gen, __ATOMIC_RELAXED, __HIP_MEMORY_SCOPE_AGENT) < target) {
      __builtin_amdgcn_s_sleep(1);
      if (++spin > (1L << 24)) break;
    }
  }
  __threadfence();
  __syncthreads();
}

// ---------------- persistent kernel ----------------

__global__ __launch_bounds__(256, 1) void scn_persistent(
    const float* __restrict__ inps, const float* __restrict__ bias0,
    const float* __restrict__ bias1, unsigned char* __restrict__ ws,
    float* __restrict__ out) {
  const int tid = threadIdx.x;
  const int wave = tid >> 6, lane = tid & 63, q = lane >> 4, l16 = lane & 15;
  const int bid = blockIdx.x;

  u16* P = (u16*)(ws + OFF_P);
  u16* H = (u16*)(ws + OFF_HST);
  float* C = (float*)(ws + OFF_CSTATE);
  const float* SC = (const float*)(ws + OFF_SC);
  unsigned* bar = (unsigned*)(ws + OFF_BAR);
  unsigned* gen = bar;
  unsigned* flags = bar + 16;
  __shared__ float red[4][4][16][16];

  // phase-A wave-unit decode (fixed across ticks): 4m x 4g x 32ft x 2bh = 1024
  const int u = bid * 4 + wave;
  const int A_bh = u & 1, A_ft = (u >> 1) & 31, A_g = (u >> 6) & 3, A_m = u >> 8;
  // phase-B block decode: 2L x 4j x 32ht = 256
  const int B_L = bid >> 7, B_j = (bid >> 5) & 3, B_ht = bid & 31;

  // ---- hoist all tick-invariant phase-A state ----
  const int fcol = A_ft * 16 + l16;
  const u16* BpA = (const u16*)(ws + (size_t)A_m * WT_BYTES) +
                   (((size_t)A_g * 512 + fcol) << 9);
  s16x8 wA[16];                       // phase-A weight fragments: 64 VGPRs
#pragma unroll
  for (int kk = 0; kk < 16; ++kk) wA[kk] = *(const s16x8*)(BpA + kk * 32 + q * 8);
  const size_t mg = (size_t)(A_m * 4 + A_g) * 64;
  const float* scp = SC + (mg << 9) + fcol;
  u16* Pp = P + (mg << 9) + fcol;
  float scr[8];
#pragma unroll
  for (int r = 0; r < 4; ++r) {
    scr[r]     = scp[(size_t)(A_bh * 32 + q * 4 + r) << 9];
    scr[r + 4] = scp[(size_t)(A_bh * 32 + q * 4 + r + 16) << 9];
  }
  const int rowA0 = A_bh * 32 + l16, rowA1 = rowA0 + 16;
  const u16* hsrc = (A_m == 2) ? (H + 32768) : H;
  const u16* hA0 = hsrc + rowA0 * 512;
  const u16* hA1 = hsrc + rowA1 * 512;
  const float* xbase0 = inps + (size_t)rowA0 * T_ * 512;
  const float* xbase1 = inps + (size_t)rowA1 * T_ * 512;

  // ---- hoist all tick-invariant phase-B state ----
  const int xp = wave >> 1, fbase = (wave & 1) * 256;  // path, K-quarter
  const int Pidx = (B_L == 0) ? xp : (3 - xp);         // L0: P0/P1 ; L1: P3/P2
  const u16* Pm = P + ((size_t)Pidx << 17);
  const u16* WtB = (const u16*)(ws + (size_t)(4 + B_L * 2 + xp) * WT_BYTES);
  s16x8 wB[4][8];                     // phase-B weight fragments: 128 VGPRs
#pragma unroll
  for (int g = 0; g < 4; ++g)
#pragma unroll
    for (int kk = 0; kk < 8; ++kk)
      wB[g][kk] = *(const s16x8*)(WtB +
          (((size_t)(g * 512 + B_ht * 16 + l16)) << 9) + fbase + kk * 32 + q * 8);
  const u16* PB[4];
#pragma unroll
  for (int g = 0; g < 4; ++g)
    PB[g] = Pm + (((size_t)(g * 64 + B_j * 16 + l16)) << 9) + fbase + q * 8;
  // epilogue constants
  const int erow = tid >> 4, ecol = tid & 15;
  const int eb = B_j * 16 + erow, eh = B_ht * 16 + ecol;
  const float* ebias = (B_L == 0) ? bias0 : bias1;
  float biasr[4];
#pragma unroll
  for (int g = 0; g < 4; ++g) biasr[g] = ebias[g * 512 + eh];
  float* ecp = C + B_L * 32768 + (size_t)eb * 512 + eh;
  u16* ehp = H + B_L * 32768 + (size_t)eb * 512 + eh;
  float* eout = out + (((size_t)eb * T_) << 9) + eh;

  unsigned target = 0;
  for (int tau = 0; tau <= T_; ++tau) {
    // ---------------- phase A : first-stage GEMMs -> P[m] ----------------
    {
      bool act = (A_m < 2) ? (tau < T_) : (tau >= 1);
      if (act) {
        f32x4 acc0 = {0.f, 0.f, 0.f, 0.f}, acc1 = {0.f, 0.f, 0.f, 0.f};
        if (A_m == 0) {  // A = x_t (fp32 from inps)
          const float* x0 = xbase0 + (size_t)tau * 512;
          const float* x1 = xbase1 + (size_t)tau * 512;
#pragma unroll 4
          for (int kk = 0; kk < 16; ++kk) {
            int k = kk * 32 + q * 8;
            acc0 = mfma_bf16(cvt8(x0 + k), wA[kk], acc0);
            acc1 = mfma_bf16(cvt8(x1 + k), wA[kk], acc1);
          }
        } else {  // A = h0 (m=1,3) or h1 (m=2), bf16 state
#pragma unroll
          for (int kk = 0; kk < 16; ++kk) {
            int k = kk * 32 + q * 8;
            acc0 = mfma_bf16(*(const s16x8*)(hA0 + k), wA[kk], acc0);
            acc1 = mfma_bf16(*(const s16x8*)(hA1 + k), wA[kk], acc1);
          }
        }
#pragma unroll
        for (int r = 0; r < 4; ++r) {
          int b0r = A_bh * 32 + q * 4 + r;
          Pp[(size_t)b0r << 9] = f2bf(acc0[r] * scr[r]);
          Pp[(size_t)(b0r + 16) << 9] = f2bf(acc1[r] * scr[r + 4]);
        }
      }
      ++target;
      gridbar(gen, flags, target, bid, tid);
    }
    // ---------------- phase B : second-stage GEMMs + gate epilogue ----------------
    {
      bool act = (B_L == 0) ? (tau < T_) : (tau >= 1);
      if (act) {
        f32x4 acc[4] = {{0.f,0.f,0.f,0.f},{0.f,0.f,0.f,0.f},
                        {0.f,0.f,0.f,0.f},{0.f,0.f,0.f,0.f}};
#pragma unroll
        for (int kk = 0; kk < 8; ++kk)
#pragma unroll
          for (int g = 0; g < 4; ++g)
            acc[g] = mfma_bf16(*(const s16x8*)(PB[g] + kk * 32), wB[g][kk], acc[g]);
#pragma unroll
        for (int g = 0; g < 4; ++g)
#pragma unroll
          for (int r = 0; r < 4; ++r)
            red[wave][g][q * 4 + r][l16] = acc[g][r];
      }
      __syncthreads();
      if (act) {
        float s[4];
#pragma unroll
        for (int g = 0; g < 4; ++g) {
          float v = biasr[g];
          v += red[0][g][erow][ecol] + red[1][g][erow][ecol] +
               red[2][g][erow][ecol] + red[3][g][erow][ecol];
          s[g] = 1.0f / (1.0f + __expf(-v));
        }
        float cprev = *ecp;
        float cn = s[0] * s[3] + s[1] * cprev;
        *ecp = cn;
        float hn = s[2] * tanhf(cn);
        *ehp = f2bf(hn);
        if (B_L == 1) {
          eout[(size_t)(tau - 1) << 9] = hn;  // out[b][t][h], t=tau-1
          if (tau == T_) {
            out[OUT_HST + eb * 1024 + 512 + eh] = hn;
            out[OUT_CST + eb * 1024 + 512 + eh] = cn;
          }
        } else if (tau == T_ - 1) {
          out[OUT_HST + eb * 1024 + eh] = hn;
          out[OUT_CST + eb * 1024 + eh] = cn;
        }
      }
      ++target;
      gridbar(gen, flags, target, bid, tid);
    }
  }
}

// ---------------- host launch ----------------

extern "C" void kernel_launch(void* const* d_in, const int* in_sizes, int n_in,
                              void* d_out, int out_size, void* d_ws, size_t ws_size,
                              hipStream_t stream) {
  const float* inps = (const float*)d_in[0];
  const float* hh   = (const float*)d_in[1];
  const float* hc   = (const float*)d_in[2];
  const float* tag  = (const float*)d_in[3];
  const float* Wa0 = (const float*)d_in[4];
  const float* Wb0 = (const float*)d_in[5];
  const float* Wc0 = (const float*)d_in[6];
  const float* Ua0 = (const float*)d_in[7];
  const float* Ub0 = (const float*)d_in[8];
  const float* Uc0 = (const float*)d_in[9];
  const float* b0  = (const float*)d_in[10];
  const float* Wa1 = (const float*)d_in[11];
  const float* Wb1 = (const float*)d_in[12];
  const float* Wc1 = (const float*)d_in[13];
  const float* Ua1 = (const float*)d_in[14];
  const float* Ub1 = (const float*)d_in[15];
  const float* Uc1 = (const float*)d_in[16];
  const float* b1  = (const float*)d_in[17];
  unsigned char* ws = (unsigned char*)d_ws;

  // transposed-weight slot order: [0]=Wc0 [1]=Uc0 [2]=Uc1 [3]=Wc1 (phase A)
  //                               [4]=Wa0 [5]=Ua0 [6]=Wa1 [7]=Ua1 (phase B)
  SrcPtrs sp;
  sp.p[0] = Wc0; sp.p[1] = Uc0; sp.p[2] = Uc1; sp.p[3] = Wc1;
  sp.p[4] = Wa0; sp.p[5] = Ua0; sp.p[6] = Wa1; sp.p[7] = Ua1;

  prep_transpose<<<dim3(2048), dim3(256), 0, stream>>>(sp, ws);
  prep_scales<<<dim3(2048), dim3(256), 0, stream>>>(tag, Wb0, Ub0, Ub1, Wb1, ws);
  prep_state<<<dim3(256), dim3(256), 0, stream>>>(hh, hc, ws);
  scn_persistent<<<dim3(256), dim3(256), 0, stream>>>(inps, b0, b1, ws, (float*)d_out);
}